// Round 1
// baseline (2148.272 us; speedup 1.0000x reference)
//
#include <hip/hip_runtime.h>

#define BSZ  2048
#define TLEN 512
#define HDIM 64
#define NG   256   // 4*H gate rows
#define NB   4     // batch rows per block

__device__ __forceinline__ float sigm(float x) {
    return __fdividef(1.0f, 1.0f + __expf(-x));
}
__device__ __forceinline__ float tanh_(float x) {
    // exact identity: tanh(x) = 1 - 2/(exp(2x)+1); stable at +/-inf
    return 1.0f - __fdividef(2.0f, __expf(2.0f * x) + 1.0f);
}

__global__ __launch_bounds__(256, 2)
void lstm2_fused(const float* __restrict__ x,
                 const float* __restrict__ w_ih0,
                 const float* __restrict__ w_hh0,
                 const float* __restrict__ b_ih0,
                 const float* __restrict__ b_hh0,
                 const float* __restrict__ w_ih1,
                 const float* __restrict__ w_hh1,
                 const float* __restrict__ b_ih1,
                 const float* __restrict__ b_hh1,
                 const float* __restrict__ fc_w,
                 const float* __restrict__ fc_b,
                 float* __restrict__ out)
{
    __shared__ float xs[NB][TLEN];     // 8 KB  staged input rows
    __shared__ float gs[NB][NG];       // 4 KB  gate scratch
    __shared__ float h1s[NB][HDIM];    // 1 KB  layer-0 hidden
    __shared__ float h2s[NB][HDIM];    // 1 KB  layer-1 hidden

    const int j  = threadIdx.x;        // gate row 0..255
    const int b0 = blockIdx.x * NB;

    // ---- stage x rows (coalesced) ----
    for (int i = j; i < NB * TLEN; i += 256) {
        const int bb = i >> 9;          // /512
        const int tt = i & (TLEN - 1);
        xs[bb][tt] = x[(b0 + bb) * TLEN + tt];
    }
    // ---- zero hidden state (NB*HDIM == 256 == blockDim) ----
    {
        const int bb = j >> 6, kk = j & 63;
        h1s[bb][kk] = 0.0f;
        h2s[bb][kk] = 0.0f;
    }

    // ---- weights register-stationary: thread j owns gate-row j ----
    float w0[HDIM], w1[HDIM], w2[HDIM];
    #pragma unroll
    for (int k = 0; k < HDIM; k += 4) {
        const float4 v0 = *(const float4*)(w_hh0 + j * HDIM + k);
        w0[k] = v0.x; w0[k+1] = v0.y; w0[k+2] = v0.z; w0[k+3] = v0.w;
        const float4 v1 = *(const float4*)(w_ih1 + j * HDIM + k);
        w1[k] = v1.x; w1[k+1] = v1.y; w1[k+2] = v1.z; w1[k+3] = v1.w;
        const float4 v2 = *(const float4*)(w_hh1 + j * HDIM + k);
        w2[k] = v2.x; w2[k+1] = v2.y; w2[k+2] = v2.z; w2[k+3] = v2.w;
    }
    const float wih0j = w_ih0[j];
    const float bias0 = b_ih0[j] + b_hh0[j];
    const float bias1 = b_ih1[j] + b_hh1[j];

    const int ub = j >> 6;   // update phase: batch row
    const int uk = j & 63;   // update phase: hidden unit
    float c1 = 0.0f, c2 = 0.0f;

    __syncthreads();

    for (int t = 0; t < TLEN; ++t) {
        float a[NB];

        // ======== layer 0 gates: a[b] = bias0 + x*w_ih0 + w_hh0 . h1 ========
        #pragma unroll
        for (int b = 0; b < NB; ++b)
            a[b] = fmaf(xs[b][t], wih0j, bias0);
        #pragma unroll
        for (int k = 0; k < HDIM; k += 4) {
            #pragma unroll
            for (int b = 0; b < NB; ++b) {
                const float4 hv = *(const float4*)&h1s[b][k];
                a[b] = fmaf(w0[k    ], hv.x, a[b]);
                a[b] = fmaf(w0[k + 1], hv.y, a[b]);
                a[b] = fmaf(w0[k + 2], hv.z, a[b]);
                a[b] = fmaf(w0[k + 3], hv.w, a[b]);
            }
        }
        #pragma unroll
        for (int b = 0; b < NB; ++b) gs[b][j] = a[b];
        __syncthreads();

        // ======== layer 0 state update (thread owns (ub,uk)) ========
        {
            const float gi = sigm (gs[ub][uk]);
            const float gf = sigm (gs[ub][64  + uk]);
            const float gg = tanh_(gs[ub][128 + uk]);
            const float go = sigm (gs[ub][192 + uk]);
            c1 = fmaf(gf, c1, gi * gg);
            h1s[ub][uk] = go * tanh_(c1);
        }
        __syncthreads();

        // ======== layer 1 gates: a[b] = bias1 + w_ih1 . h1_new + w_hh1 . h2 ========
        #pragma unroll
        for (int b = 0; b < NB; ++b) a[b] = bias1;
        #pragma unroll
        for (int k = 0; k < HDIM; k += 4) {
            #pragma unroll
            for (int b = 0; b < NB; ++b) {
                const float4 h1v = *(const float4*)&h1s[b][k];
                a[b] = fmaf(w1[k    ], h1v.x, a[b]);
                a[b] = fmaf(w1[k + 1], h1v.y, a[b]);
                a[b] = fmaf(w1[k + 2], h1v.z, a[b]);
                a[b] = fmaf(w1[k + 3], h1v.w, a[b]);
                const float4 h2v = *(const float4*)&h2s[b][k];
                a[b] = fmaf(w2[k    ], h2v.x, a[b]);
                a[b] = fmaf(w2[k + 1], h2v.y, a[b]);
                a[b] = fmaf(w2[k + 2], h2v.z, a[b]);
                a[b] = fmaf(w2[k + 3], h2v.w, a[b]);
            }
        }
        #pragma unroll
        for (int b = 0; b < NB; ++b) gs[b][j] = a[b];
        __syncthreads();

        // ======== layer 1 state update ========
        {
            const float gi = sigm (gs[ub][uk]);
            const float gf = sigm (gs[ub][64  + uk]);
            const float gg = tanh_(gs[ub][128 + uk]);
            const float go = sigm (gs[ub][192 + uk]);
            c2 = fmaf(gf, c2, gi * gg);
            h2s[ub][uk] = go * tanh_(c2);
        }
        __syncthreads();
    }

    // ======== final FC on last h2 ========
    if (j < NB) {
        float s = fc_b[0];
        #pragma unroll
        for (int k = 0; k < HDIM; ++k)
            s = fmaf(fc_w[k], h2s[j][k], s);
        out[b0 + j] = s;
    }
}

extern "C" void kernel_launch(void* const* d_in, const int* in_sizes, int n_in,
                              void* d_out, int out_size, void* d_ws, size_t ws_size,
                              hipStream_t stream) {
    const float* xp     = (const float*)d_in[0];
    const float* w_ih0  = (const float*)d_in[1];
    const float* w_hh0  = (const float*)d_in[2];
    const float* b_ih0  = (const float*)d_in[3];
    const float* b_hh0  = (const float*)d_in[4];
    const float* w_ih1  = (const float*)d_in[5];
    const float* w_hh1  = (const float*)d_in[6];
    const float* b_ih1  = (const float*)d_in[7];
    const float* b_hh1  = (const float*)d_in[8];
    const float* fc_w   = (const float*)d_in[9];
    const float* fc_b   = (const float*)d_in[10];
    float* outp = (float*)d_out;

    dim3 grid(BSZ / NB);   // 512 blocks
    dim3 block(256);
    lstm2_fused<<<grid, block, 0, stream>>>(xp, w_ih0, w_hh0, b_ih0, b_hh0,
                                            w_ih1, w_hh1, b_ih1, b_hh1,
                                            fc_w, fc_b, outp);
}